// Round 1
// baseline (273.105 us; speedup 1.0000x reference)
//
#include <hip/hip_runtime.h>
#include <math.h>

// ws layout (floats)
#define WS_WEFF 0        // 45 cfgs * 225 taps = 10125
#define WS_M    10240    // 4 * 961 = 3844
#define WS_OFF  14336    // off0[4], off1[4]

// ---------------------------------------------------------------------------
// Kernel A: precompute routing -> we/wc -> T -> 45 clipped composed kernels,
// 4-parity MLP -> offsets + per-class mix matrices M.
// ---------------------------------------------------------------------------
__global__ void prep_kernel(
    const float* __restrict__ WE,  const float* __restrict__ WC,
    const float* __restrict__ W2,
    const float* __restrict__ bw1, const float* __restrict__ bb1,
    const float* __restrict__ bw2, const float* __restrict__ bb2,
    const float* __restrict__ r2w, const float* __restrict__ r2b,
    const float* __restrict__ ow,  const float* __restrict__ ob,
    const float* __restrict__ l1w, const float* __restrict__ l1b,
    const float* __restrict__ l2w, const float* __restrict__ l2b,
    float* __restrict__ ws)
{
    __shared__ float weL[1440], wcL[1440], TL[2025], r2cL[16];
    const int tid = threadIdx.x;

    // ---- routing rsum (computed redundantly per thread; tiny) ----
    float rsum[4];
    {
        float rw[2][4];
        for (int r = 0; r < 2; ++r) {
            float chv = r ? 0.25f : -0.25f;
            float a0 = l2b[0], a1 = l2b[1], a2 = l2b[2], a3 = l2b[3];
            for (int o = 0; o < 64; ++o) {
                float h = fmaxf(0.5f*l1w[2*o] + chv*l1w[2*o+1] + l1b[o], 0.0f);
                a0 += h*l2w[o];     a1 += h*l2w[64+o];
                a2 += h*l2w[128+o]; a3 += h*l2w[192+o];
            }
            float mx = fmaxf(fmaxf(a0,a1), fmaxf(a2,a3));
            float e0=expf(a0-mx), e1=expf(a1-mx), e2=expf(a2-mx), e3=expf(a3-mx);
            float s = e0+e1+e2+e3;
            rw[r][0]=e0/s; rw[r][1]=e1/s; rw[r][2]=e2/s; rw[r][3]=e3/s;
        }
        for (int e = 0; e < 4; ++e) rsum[e] = rw[0][e] + rw[1][e];
    }

    // ---- we[k][t], wc[k][t] (t = dd*9+ry*3+rx, 45 taps) ----
    for (int idx = tid; idx < 1440; idx += 256) {
        float a = 0.f, b = 0.f;
        for (int e = 0; e < 4; ++e) {
            a += rsum[e] * WE[e*1440 + idx];
            b += rsum[e] * WC[e*1440 + idx];
        }
        weL[idx] = a; wcL[idx] = b;
    }
    __syncthreads();

    // ---- T[s][t] = sum_k wc[k][s] * we[k][t] ----
    for (int idx = tid; idx < 2025; idx += 256) {
        int s = idx / 45, t = idx % 45;
        float acc = 0.f;
        for (int k = 0; k < 32; ++k) acc += wcL[k*45+s] * weL[k*45+t];
        TL[idx] = acc;
    }
    __syncthreads();

    // ---- 45 clipped composed kernels: cfg = a*9 + b*3 + c, u = ud*25+uy*5+ux ----
    for (int idx = tid; idx < 10125; idx += 256) {
        int cfg = idx / 225, u = idx % 225;
        int a = cfg/9, b = (cfg%9)/3, c = cfg%3;
        int ud = u/25, uy = (u%25)/5, ux = u%5;
        int sdlo = (a==0)?2:((a==1)?1:0);
        int sdhi = (a==4)?2:((a==3)?3:4);
        int sylo = (b==0)?1:0, syhi = (b==2)?1:2;
        int sxlo = (c==0)?1:0, sxhi = (c==2)?1:2;
        if (sdlo < ud-4) sdlo = ud-4;
        if (sdhi > ud)   sdhi = ud;
        if (sylo < uy-2) sylo = uy-2;
        if (syhi > uy)   syhi = uy;
        if (sxlo < ux-2) sxlo = ux-2;
        if (sxhi > ux)   sxhi = ux;
        float acc = 0.f;
        for (int sd = sdlo; sd <= sdhi; ++sd)
            for (int sy = sylo; sy <= syhi; ++sy)
                for (int sx = sxlo; sx <= sxhi; ++sx)
                    acc += TL[(sd*9+sy*3+sx)*45 + (ud-sd)*9 + (uy-sy)*3 + (ux-sx)];
        ws[WS_WEFF + idx] = acc;
    }

    // ---- 4-parity MLP: offsets + r2 (cls = (y&1)*2 + (x&1)) ----
    if (tid < 4) {
        float chv = (tid & 2) ? 0.25f : -0.25f;   // y parity
        float cwv = (tid & 1) ? 0.25f : -0.25f;   // x parity
        float e1[64], e2[64];
        for (int o = 0; o < 64; ++o)
            e1[o] = fmaxf(0.5f*bw1[3*o] + chv*bw1[3*o+1] + cwv*bw1[3*o+2] + bb1[o], 0.f);
        for (int o = 0; o < 64; ++o) {
            float acc = bb2[o];
            for (int i = 0; i < 64; ++i) acc += e1[i]*bw2[64*o+i];
            e2[o] = fmaxf(acc, 0.f);
        }
        float o0 = ob[0], o1 = ob[1];
        for (int i = 0; i < 64; ++i) { o0 += e2[i]*ow[i]; o1 += e2[i]*ow[64+i]; }
        ws[WS_OFF + tid]     = o0;   // x offset
        ws[WS_OFF + 4 + tid] = o1;   // y offset
        for (int e = 0; e < 4; ++e) {
            float acc = r2b[e];
            for (int i = 0; i < 64; ++i) acc += e2[i]*r2w[64*e+i];
            r2cL[tid*4+e] = 1.f/(1.f+expf(-acc));
        }
    }
    __syncthreads();

    // ---- M[cls][i][j] = sum_e r2c[cls][e] * W2[e][i][j] ----
    for (int idx = tid; idx < 3844; idx += 256) {
        int cls = idx / 961, ij = idx % 961;
        float acc = 0.f;
        for (int e = 0; e < 4; ++e) acc += r2cL[cls*4+e]*W2[e*961+ij];
        ws[WS_M + idx] = acc;
    }
}

// ---------------------------------------------------------------------------
// Kernel B: per 8x32 pixel tile: bilinear fill -> composed 9x5x5 conv (all 31
// depth channels per thread, register column reuse) -> residual -> 31x31 mix.
// ---------------------------------------------------------------------------
__global__ __launch_bounds__(256, 2)
void fused_kernel(const float* __restrict__ x, const float* __restrict__ ws,
                  float* __restrict__ out)
{
    __shared__ float fs[31][12][36];   // fea tile, y/x halo 2 (zero outside domain)
    __shared__ float Ms[3844];
    const int tid = threadIdx.x;
    const int x0 = blockIdx.x * 32;
    const int y0 = blockIdx.y * 8;

    float off0[4], off1[4];
    #pragma unroll
    for (int c = 0; c < 4; ++c) { off0[c] = ws[WS_OFF+c]; off1[c] = ws[WS_OFF+4+c]; }

    for (int idx = tid; idx < 3844; idx += 256) Ms[idx] = ws[WS_M + idx];

    // ---- bilinear fill of the fea tile ----
    for (int idx = tid; idx < 13392; idx += 256) {
        int c  = idx / 432;
        int r  = idx % 432;
        int yy = r / 36, xx = r % 36;
        int gy = y0 + yy - 2, gx = x0 + xx - 2;
        float v = 0.f;
        if (gy >= 0 && gy < 256 && gx >= 0 && gx < 256) {
            int cls = ((gy & 1) << 1) | (gx & 1);
            float ix = (gx + 0.5f)*0.5f - 0.5f + off0[cls];
            float iy = (gy + 0.5f)*0.5f - 0.5f + off1[cls];
            float xf = floorf(ix), yf = floorf(iy);
            float wx = ix - xf, wy = iy - yf;
            int xi = (int)xf, yi = (int)yf;
            const float* xc = x + c*16384;
            float acc = 0.f;
            if (yi   >= 0 && yi   < 128 && xi   >= 0 && xi   < 128) acc += xc[yi*128+xi]       * (1.f-wy)*(1.f-wx);
            if (yi   >= 0 && yi   < 128 && xi+1 >= 0 && xi+1 < 128) acc += xc[yi*128+xi+1]     * (1.f-wy)*wx;
            if (yi+1 >= 0 && yi+1 < 128 && xi   >= 0 && xi   < 128) acc += xc[(yi+1)*128+xi]   * wy*(1.f-wx);
            if (yi+1 >= 0 && yi+1 < 128 && xi+1 >= 0 && xi+1 < 128) acc += xc[(yi+1)*128+xi+1] * wy*wx;
            v = acc;
        }
        ((float*)fs)[idx] = v;
    }
    __syncthreads();

    const int lx = tid & 31, ly = tid >> 5;
    const int gx = x0 + lx, gy = y0 + ly;
    const int bcls = (gy == 0) ? 0 : ((gy == 255) ? 2 : 1);
    const int ccls = (gx == 0) ? 0 : ((gx == 255) ? 2 : 1);
    const float* weff = ws + WS_WEFF;
    const int cfgb0 = (bcls*3 + ccls) * 225;     // + a*2025 selects d-class

    float o2[31];
    #pragma unroll
    for (int d = 0; d < 31; ++d) o2[d] = fs[d][ly+2][lx+2];   // conv2 residual (+fea)

    #pragma unroll 1
    for (int uy = 0; uy < 5; ++uy) {
        #pragma unroll 1
        for (int ux = 0; ux < 5; ++ux) {
            float col[39];
            #pragma unroll
            for (int i = 0; i < 39; ++i)
                col[i] = (i >= 4 && i < 35) ? fs[i-4][ly+uy][lx+ux] : 0.f;
            const int uo = uy*5 + ux;
            float w9[9];
            #pragma unroll
            for (int ud = 0; ud < 9; ++ud) w9[ud] = weff[cfgb0 + 2*2025 + ud*25 + uo];
            #pragma unroll
            for (int d = 2; d < 29; ++d) {
                #pragma unroll
                for (int ud = 0; ud < 9; ++ud)
                    o2[d] += w9[ud] * col[d+ud];
            }
            #pragma unroll
            for (int ud = 0; ud < 9; ++ud) {
                o2[0]  += weff[cfgb0 + 0*2025 + ud*25 + uo] * col[ud];
                o2[1]  += weff[cfgb0 + 1*2025 + ud*25 + uo] * col[1+ud];
                o2[29] += weff[cfgb0 + 3*2025 + ud*25 + uo] * col[29+ud];
                o2[30] += weff[cfgb0 + 4*2025 + ud*25 + uo] * col[30+ud];
            }
        }
    }

    // ---- mix: out[i] = sum_j M[cls][i][j]*o2[j] + fea0[i] ----
    const int cls = ((gy & 1) << 1) | (gx & 1);
    #pragma unroll 1
    for (int i = 0; i < 31; ++i) {
        float acc = fs[i][ly+2][lx+2];
        #pragma unroll
        for (int j = 0; j < 31; ++j) acc += Ms[cls*961 + i*31 + j] * o2[j];
        out[i*65536 + gy*256 + gx] = acc;
    }
}

extern "C" void kernel_launch(void* const* d_in, const int* in_sizes, int n_in,
                              void* d_out, int out_size, void* d_ws, size_t ws_size,
                              hipStream_t stream)
{
    const float* x   = (const float*)d_in[0];
    // d_in[1] = scale (int, always 2; shapes are compile-time)
    const float* WE  = (const float*)d_in[2];
    const float* WC  = (const float*)d_in[3];
    const float* W2  = (const float*)d_in[4];
    const float* bw1 = (const float*)d_in[5];
    const float* bb1 = (const float*)d_in[6];
    const float* bw2 = (const float*)d_in[7];
    const float* bb2 = (const float*)d_in[8];
    const float* r2w = (const float*)d_in[9];
    const float* r2b = (const float*)d_in[10];
    const float* ow  = (const float*)d_in[11];
    const float* ob  = (const float*)d_in[12];
    const float* l1w = (const float*)d_in[13];
    const float* l1b = (const float*)d_in[14];
    const float* l2w = (const float*)d_in[15];
    const float* l2b = (const float*)d_in[16];
    float* ws  = (float*)d_ws;
    float* out = (float*)d_out;

    hipLaunchKernelGGL(prep_kernel, dim3(1), dim3(256), 0, stream,
                       WE, WC, W2, bw1, bb1, bw2, bb2, r2w, r2b,
                       ow, ob, l1w, l1b, l2w, l2b, ws);
    hipLaunchKernelGGL(fused_kernel, dim3(8, 32), dim3(256), 0, stream,
                       x, ws, out);
}

// Round 2
// 177.447 us; speedup vs baseline: 1.5391x; 1.5391x over previous
//
#include <hip/hip_runtime.h>
#include <math.h>

// ws layout (floats)
#define WS_WEFF 0        // 45 cfgs * 225 taps = 10125
#define WS_M    10240    // 4 * 961 = 3844
#define WS_OFF  14336    // off0[4], off1[4]

// ---------------------------------------------------------------------------
// Kernel A (8 blocks x 256): routing + 4-parity MLP via wave reductions;
// weL/wcL/T recomputed per block (cheap); 45 clipped composed kernels and M
// partitioned across blocks.
// ---------------------------------------------------------------------------
__global__ void prep_kernel(
    const float* __restrict__ WE,  const float* __restrict__ WC,
    const float* __restrict__ W2,
    const float* __restrict__ bw1, const float* __restrict__ bb1,
    const float* __restrict__ bw2, const float* __restrict__ bb2,
    const float* __restrict__ r2w, const float* __restrict__ r2b,
    const float* __restrict__ ow,  const float* __restrict__ ob,
    const float* __restrict__ l1w, const float* __restrict__ l1b,
    const float* __restrict__ l2w, const float* __restrict__ l2b,
    float* __restrict__ ws)
{
    __shared__ float weL[1440], wcL[1440], TL[2025];
    __shared__ float e1L[4][64];
    __shared__ float r2cL[16], rsumS[4], logitsL[2][4];
    const int tid  = threadIdx.x;
    const int bid  = blockIdx.x;
    const int lane = tid & 63, wid = tid >> 6;

    // ---- routing logits: wave r in {0,1}, one hidden unit per lane ----
    if (wid < 2) {
        float chv = wid ? 0.25f : -0.25f;
        int o = lane;
        float h = fmaxf(0.5f*l1w[2*o] + chv*l1w[2*o+1] + l1b[o], 0.f);
        float a0 = h*l2w[o], a1 = h*l2w[64+o], a2 = h*l2w[128+o], a3 = h*l2w[192+o];
        for (int off = 32; off; off >>= 1) {
            a0 += __shfl_down(a0, off); a1 += __shfl_down(a1, off);
            a2 += __shfl_down(a2, off); a3 += __shfl_down(a3, off);
        }
        if (lane == 0) {
            logitsL[wid][0] = a0 + l2b[0]; logitsL[wid][1] = a1 + l2b[1];
            logitsL[wid][2] = a2 + l2b[2]; logitsL[wid][3] = a3 + l2b[3];
        }
    }

    // ---- body MLP layer 1: wave = parity class, one hidden unit per lane ----
    {
        float chv = (wid & 2) ? 0.25f : -0.25f;   // y parity
        float cwv = (wid & 1) ? 0.25f : -0.25f;   // x parity
        int o = lane;
        e1L[wid][o] = fmaxf(0.5f*bw1[3*o] + chv*bw1[3*o+1] + cwv*bw1[3*o+2] + bb1[o], 0.f);
    }
    __syncthreads();

    // ---- softmax + rsum (serial, tiny) ----
    if (tid == 0) {
        float rs[4] = {0.f,0.f,0.f,0.f};
        for (int r = 0; r < 2; ++r) {
            float l0=logitsL[r][0], l1v=logitsL[r][1], l2v=logitsL[r][2], l3=logitsL[r][3];
            float mx = fmaxf(fmaxf(l0,l1v), fmaxf(l2v,l3));
            float e0=expf(l0-mx), e1=expf(l1v-mx), e2=expf(l2v-mx), e3=expf(l3-mx);
            float s = e0+e1+e2+e3;
            rs[0]+=e0/s; rs[1]+=e1/s; rs[2]+=e2/s; rs[3]+=e3/s;
        }
        rsumS[0]=rs[0]; rsumS[1]=rs[1]; rsumS[2]=rs[2]; rsumS[3]=rs[3];
    }

    // ---- MLP layer 2 + offsets + r2 via wave reductions ----
    {
        int o = lane;
        float acc = bb2[o];
        #pragma unroll 8
        for (int i = 0; i < 64; ++i) acc += e1L[wid][i]*bw2[o*64+i];
        float e2v = fmaxf(acc, 0.f);
        float v0 = e2v*ow[o],       v1 = e2v*ow[64+o];
        float r0 = e2v*r2w[o],      r1 = e2v*r2w[64+o];
        float r2v= e2v*r2w[128+o],  r3 = e2v*r2w[192+o];
        for (int off = 32; off; off >>= 1) {
            v0 += __shfl_down(v0, off);  v1 += __shfl_down(v1, off);
            r0 += __shfl_down(r0, off);  r1 += __shfl_down(r1, off);
            r2v+= __shfl_down(r2v, off); r3 += __shfl_down(r3, off);
        }
        if (lane == 0) {
            if (bid == 0) { ws[WS_OFF + wid] = v0 + ob[0]; ws[WS_OFF + 4 + wid] = v1 + ob[1]; }
            r2cL[wid*4+0] = 1.f/(1.f+expf(-(r0 + r2b[0])));
            r2cL[wid*4+1] = 1.f/(1.f+expf(-(r1 + r2b[1])));
            r2cL[wid*4+2] = 1.f/(1.f+expf(-(r2v+ r2b[2])));
            r2cL[wid*4+3] = 1.f/(1.f+expf(-(r3 + r2b[3])));
        }
    }
    __syncthreads();

    // ---- we/wc (routing-combined conv weights), full copy per block ----
    {
        float rs0=rsumS[0], rs1=rsumS[1], rs2=rsumS[2], rs3=rsumS[3];
        for (int idx = tid; idx < 1440; idx += 256) {
            weL[idx] = rs0*WE[idx] + rs1*WE[1440+idx] + rs2*WE[2880+idx] + rs3*WE[4320+idx];
            wcL[idx] = rs0*WC[idx] + rs1*WC[1440+idx] + rs2*WC[2880+idx] + rs3*WC[4320+idx];
        }
    }
    __syncthreads();

    // ---- T[s][t] = sum_k wc[k][s]*we[k][t], full per block ----
    for (int idx = tid; idx < 2025; idx += 256) {
        int s = idx / 45, t = idx % 45;
        float acc = 0.f;
        #pragma unroll 8
        for (int k = 0; k < 32; ++k) acc += wcL[k*45+s] * weL[k*45+t];
        TL[idx] = acc;
    }
    __syncthreads();

    // ---- 45 clipped composed kernels, partitioned across blocks ----
    {
        const int c0 = bid*1266, c1 = (c0+1266 < 10125) ? c0+1266 : 10125;
        for (int idx = c0 + tid; idx < c1; idx += 256) {
            int cfg = idx / 225, u = idx % 225;
            int a = cfg/9, b = (cfg%9)/3, c = cfg%3;
            int ud = u/25, uy = (u%25)/5, ux = u%5;
            int sdlo = (a==0)?2:((a==1)?1:0);
            int sdhi = (a==4)?2:((a==3)?3:4);
            int sylo = (b==0)?1:0, syhi = (b==2)?1:2;
            int sxlo = (c==0)?1:0, sxhi = (c==2)?1:2;
            if (sdlo < ud-4) sdlo = ud-4;
            if (sdhi > ud)   sdhi = ud;
            if (sylo < uy-2) sylo = uy-2;
            if (syhi > uy)   syhi = uy;
            if (sxlo < ux-2) sxlo = ux-2;
            if (sxhi > ux)   sxhi = ux;
            float acc = 0.f;
            for (int sd = sdlo; sd <= sdhi; ++sd)
                for (int sy = sylo; sy <= syhi; ++sy)
                    for (int sx = sxlo; sx <= sxhi; ++sx)
                        acc += TL[(sd*9+sy*3+sx)*45 + (ud-sd)*9 + (uy-sy)*3 + (ux-sx)];
            ws[WS_WEFF + idx] = acc;
        }
    }

    // ---- M[cls][i][j] = sum_e r2c[cls][e]*W2[e][i][j], partitioned ----
    {
        const int c0 = bid*481, c1 = (c0+481 < 3844) ? c0+481 : 3844;
        for (int idx = c0 + tid; idx < c1; idx += 256) {
            int cls = idx / 961, ij = idx % 961;
            float acc = 0.f;
            #pragma unroll
            for (int e = 0; e < 4; ++e) acc += r2cL[cls*4+e]*W2[e*961+ij];
            ws[WS_M + idx] = acc;
        }
    }
}

// ---------------------------------------------------------------------------
// Kernel B: per 8x32 pixel tile: bilinear fill + LDS-stage weff/M -> composed
// 9x5x5 conv (register column reuse along depth) -> residual -> 31x31 mix.
// ---------------------------------------------------------------------------
__global__ __launch_bounds__(256, 1)
void fused_kernel(const float* __restrict__ x, const float* __restrict__ ws,
                  float* __restrict__ out)
{
    __shared__ float fs[31][12][36];   // 53.6 KB fea tile, halo 2 (zero outside)
    __shared__ float Ms[3844];         // 15.4 KB
    __shared__ float weffL[10125];     // 40.5 KB
    const int tid = threadIdx.x;
    const int x0 = blockIdx.x * 32;
    const int y0 = blockIdx.y * 8;

    float off0[4], off1[4];
    #pragma unroll
    for (int c = 0; c < 4; ++c) { off0[c] = ws[WS_OFF+c]; off1[c] = ws[WS_OFF+4+c]; }

    for (int idx = tid; idx < 10125; idx += 256) weffL[idx] = ws[WS_WEFF + idx];
    for (int idx = tid; idx < 3844;  idx += 256) Ms[idx]    = ws[WS_M + idx];

    // ---- bilinear fill of the fea tile ----
    for (int idx = tid; idx < 13392; idx += 256) {
        int c  = idx / 432;
        int r  = idx % 432;
        int yy = r / 36, xx = r % 36;
        int gy = y0 + yy - 2, gx = x0 + xx - 2;
        float v = 0.f;
        if (gy >= 0 && gy < 256 && gx >= 0 && gx < 256) {
            int cls = ((gy & 1) << 1) | (gx & 1);
            float ix = (gx + 0.5f)*0.5f - 0.5f + off0[cls];
            float iy = (gy + 0.5f)*0.5f - 0.5f + off1[cls];
            float xf = floorf(ix), yf = floorf(iy);
            float wx = ix - xf, wy = iy - yf;
            int xi = (int)xf, yi = (int)yf;
            const float* xc = x + c*16384;
            float acc = 0.f;
            if (yi   >= 0 && yi   < 128 && xi   >= 0 && xi   < 128) acc += xc[yi*128+xi]       * (1.f-wy)*(1.f-wx);
            if (yi   >= 0 && yi   < 128 && xi+1 >= 0 && xi+1 < 128) acc += xc[yi*128+xi+1]     * (1.f-wy)*wx;
            if (yi+1 >= 0 && yi+1 < 128 && xi   >= 0 && xi   < 128) acc += xc[(yi+1)*128+xi]   * wy*(1.f-wx);
            if (yi+1 >= 0 && yi+1 < 128 && xi+1 >= 0 && xi+1 < 128) acc += xc[(yi+1)*128+xi+1] * wy*wx;
            v = acc;
        }
        ((float*)fs)[idx] = v;
    }
    __syncthreads();

    const int lx = tid & 31, ly = tid >> 5;
    const int gx = x0 + lx, gy = y0 + ly;
    const int bcls = (gy == 0) ? 0 : ((gy == 255) ? 2 : 1);
    const int ccls = (gx == 0) ? 0 : ((gx == 255) ? 2 : 1);
    const int cfgb0 = (bcls*3 + ccls) * 225;     // + a*2025 selects d-class

    float o2[31];
    #pragma unroll
    for (int d = 0; d < 31; ++d) o2[d] = fs[d][ly+2][lx+2];   // conv2 residual (+fea)

    #pragma unroll 1
    for (int uy = 0; uy < 5; ++uy) {
        #pragma unroll 1
        for (int ux = 0; ux < 5; ++ux) {
            float col[39];
            #pragma unroll
            for (int i = 0; i < 39; ++i)
                col[i] = (i >= 4 && i < 35) ? fs[i-4][ly+uy][lx+ux] : 0.f;
            const int uo = uy*5 + ux;
            float w9[9];
            #pragma unroll
            for (int ud = 0; ud < 9; ++ud) w9[ud] = weffL[cfgb0 + 2*2025 + ud*25 + uo];
            #pragma unroll
            for (int d = 2; d < 29; ++d) {
                #pragma unroll
                for (int ud = 0; ud < 9; ++ud)
                    o2[d] += w9[ud] * col[d+ud];
            }
            #pragma unroll
            for (int ud = 0; ud < 9; ++ud) {
                o2[0]  += weffL[cfgb0 + 0*2025 + ud*25 + uo] * col[ud];
                o2[1]  += weffL[cfgb0 + 1*2025 + ud*25 + uo] * col[1+ud];
                o2[29] += weffL[cfgb0 + 3*2025 + ud*25 + uo] * col[29+ud];
                o2[30] += weffL[cfgb0 + 4*2025 + ud*25 + uo] * col[30+ud];
            }
        }
    }

    // ---- mix: out[i] = sum_j M[cls][i][j]*o2[j] + fea0[i] ----
    const int cls = ((gy & 1) << 1) | (gx & 1);
    #pragma unroll 1
    for (int i = 0; i < 31; ++i) {
        float acc = fs[i][ly+2][lx+2];
        #pragma unroll
        for (int j = 0; j < 31; ++j) acc += Ms[cls*961 + i*31 + j] * o2[j];
        out[i*65536 + gy*256 + gx] = acc;
    }
}

extern "C" void kernel_launch(void* const* d_in, const int* in_sizes, int n_in,
                              void* d_out, int out_size, void* d_ws, size_t ws_size,
                              hipStream_t stream)
{
    const float* x   = (const float*)d_in[0];
    // d_in[1] = scale (int, always 2; shapes are compile-time)
    const float* WE  = (const float*)d_in[2];
    const float* WC  = (const float*)d_in[3];
    const float* W2  = (const float*)d_in[4];
    const float* bw1 = (const float*)d_in[5];
    const float* bb1 = (const float*)d_in[6];
    const float* bw2 = (const float*)d_in[7];
    const float* bb2 = (const float*)d_in[8];
    const float* r2w = (const float*)d_in[9];
    const float* r2b = (const float*)d_in[10];
    const float* ow  = (const float*)d_in[11];
    const float* ob  = (const float*)d_in[12];
    const float* l1w = (const float*)d_in[13];
    const float* l1b = (const float*)d_in[14];
    const float* l2w = (const float*)d_in[15];
    const float* l2b = (const float*)d_in[16];
    float* ws  = (float*)d_ws;
    float* out = (float*)d_out;

    hipLaunchKernelGGL(prep_kernel, dim3(8), dim3(256), 0, stream,
                       WE, WC, W2, bw1, bb1, bw2, bb2, r2w, r2b,
                       ow, ob, l1w, l1b, l2w, l2b, ws);
    hipLaunchKernelGGL(fused_kernel, dim3(8, 32), dim3(256), 0, stream,
                       x, ws, out);
}

// Round 5
// 173.282 us; speedup vs baseline: 1.5761x; 1.0240x over previous
//
#include <hip/hip_runtime.h>
#include <math.h>

// ws layout (floats)
#define WS_WEFF 0        // 45 cfgs * 225 taps = 10125
#define WS_M    10240    // 4 * 961 = 3844
#define WS_OFF  14336    // off0[4], off1[4]

// ---------------------------------------------------------------------------
// Kernel A (16 blocks x 256): routing + 4-parity MLP via wave reductions;
// weL/wcL/T recomputed per block (cheap); 45 clipped composed kernels and M
// partitioned across blocks.
// ---------------------------------------------------------------------------
__global__ void prep_kernel(
    const float* __restrict__ WE,  const float* __restrict__ WC,
    const float* __restrict__ W2,
    const float* __restrict__ bw1, const float* __restrict__ bb1,
    const float* __restrict__ bw2, const float* __restrict__ bb2,
    const float* __restrict__ r2w, const float* __restrict__ r2b,
    const float* __restrict__ ow,  const float* __restrict__ ob,
    const float* __restrict__ l1w, const float* __restrict__ l1b,
    const float* __restrict__ l2w, const float* __restrict__ l2b,
    float* __restrict__ ws)
{
    __shared__ float weL[1440], wcL[1440], TL[2025];
    __shared__ float e1L[4][64];
    __shared__ float r2cL[16], rsumS[4], logitsL[2][4];
    const int tid  = threadIdx.x;
    const int bid  = blockIdx.x;
    const int lane = tid & 63, wid = tid >> 6;

    // ---- routing logits: wave r in {0,1}, one hidden unit per lane ----
    if (wid < 2) {
        float chv = wid ? 0.25f : -0.25f;
        int o = lane;
        float h = fmaxf(0.5f*l1w[2*o] + chv*l1w[2*o+1] + l1b[o], 0.f);
        float a0 = h*l2w[o], a1 = h*l2w[64+o], a2 = h*l2w[128+o], a3 = h*l2w[192+o];
        for (int off = 32; off; off >>= 1) {
            a0 += __shfl_down(a0, off); a1 += __shfl_down(a1, off);
            a2 += __shfl_down(a2, off); a3 += __shfl_down(a3, off);
        }
        if (lane == 0) {
            logitsL[wid][0] = a0 + l2b[0]; logitsL[wid][1] = a1 + l2b[1];
            logitsL[wid][2] = a2 + l2b[2]; logitsL[wid][3] = a3 + l2b[3];
        }
    }

    // ---- body MLP layer 1: wave = parity class, one hidden unit per lane ----
    {
        float chv = (wid & 2) ? 0.25f : -0.25f;   // y parity
        float cwv = (wid & 1) ? 0.25f : -0.25f;   // x parity
        int o = lane;
        e1L[wid][o] = fmaxf(0.5f*bw1[3*o] + chv*bw1[3*o+1] + cwv*bw1[3*o+2] + bb1[o], 0.f);
    }
    __syncthreads();

    // ---- softmax + rsum (serial, tiny) ----
    if (tid == 0) {
        float rs[4] = {0.f,0.f,0.f,0.f};
        for (int r = 0; r < 2; ++r) {
            float l0=logitsL[r][0], l1v=logitsL[r][1], l2v=logitsL[r][2], l3=logitsL[r][3];
            float mx = fmaxf(fmaxf(l0,l1v), fmaxf(l2v,l3));
            float e0=expf(l0-mx), e1=expf(l1v-mx), e2=expf(l2v-mx), e3=expf(l3-mx);
            float s = e0+e1+e2+e3;
            rs[0]+=e0/s; rs[1]+=e1/s; rs[2]+=e2/s; rs[3]+=e3/s;
        }
        rsumS[0]=rs[0]; rsumS[1]=rs[1]; rsumS[2]=rs[2]; rsumS[3]=rs[3];
    }

    // ---- MLP layer 2 + offsets + r2 via wave reductions ----
    {
        int o = lane;
        float acc = bb2[o];
        #pragma unroll 8
        for (int i = 0; i < 64; ++i) acc += e1L[wid][i]*bw2[o*64+i];
        float e2v = fmaxf(acc, 0.f);
        float v0 = e2v*ow[o],       v1 = e2v*ow[64+o];
        float r0 = e2v*r2w[o],      r1 = e2v*r2w[64+o];
        float r2v= e2v*r2w[128+o],  r3 = e2v*r2w[192+o];
        for (int off = 32; off; off >>= 1) {
            v0 += __shfl_down(v0, off);  v1 += __shfl_down(v1, off);
            r0 += __shfl_down(r0, off);  r1 += __shfl_down(r1, off);
            r2v+= __shfl_down(r2v, off); r3 += __shfl_down(r3, off);
        }
        if (lane == 0) {
            if (bid == 0) { ws[WS_OFF + wid] = v0 + ob[0]; ws[WS_OFF + 4 + wid] = v1 + ob[1]; }
            r2cL[wid*4+0] = 1.f/(1.f+expf(-(r0 + r2b[0])));
            r2cL[wid*4+1] = 1.f/(1.f+expf(-(r1 + r2b[1])));
            r2cL[wid*4+2] = 1.f/(1.f+expf(-(r2v+ r2b[2])));
            r2cL[wid*4+3] = 1.f/(1.f+expf(-(r3 + r2b[3])));
        }
    }
    __syncthreads();

    // ---- we/wc (routing-combined conv weights), full copy per block ----
    {
        float rs0=rsumS[0], rs1=rsumS[1], rs2=rsumS[2], rs3=rsumS[3];
        for (int idx = tid; idx < 1440; idx += 256) {
            weL[idx] = rs0*WE[idx] + rs1*WE[1440+idx] + rs2*WE[2880+idx] + rs3*WE[4320+idx];
            wcL[idx] = rs0*WC[idx] + rs1*WC[1440+idx] + rs2*WC[2880+idx] + rs3*WC[4320+idx];
        }
    }
    __syncthreads();

    // ---- T[s][t] = sum_k wc[k][s]*we[k][t], full per block ----
    for (int idx = tid; idx < 2025; idx += 256) {
        int s = idx / 45, t = idx % 45;
        float acc = 0.f;
        #pragma unroll 8
        for (int k = 0; k < 32; ++k) acc += wcL[k*45+s] * weL[k*45+t];
        TL[idx] = acc;
    }
    __syncthreads();

    // ---- 45 clipped composed kernels, partitioned across blocks ----
    {
        const int c0 = bid*633, c1 = (c0+633 < 10125) ? c0+633 : 10125;
        for (int idx = c0 + tid; idx < c1; idx += 256) {
            int cfg = idx / 225, u = idx % 225;
            int a = cfg/9, b = (cfg%9)/3, c = cfg%3;
            int ud = u/25, uy = (u%25)/5, ux = u%5;
            int sdlo = (a==0)?2:((a==1)?1:0);
            int sdhi = (a==4)?2:((a==3)?3:4);
            int sylo = (b==0)?1:0, syhi = (b==2)?1:2;
            int sxlo = (c==0)?1:0, sxhi = (c==2)?1:2;
            if (sdlo < ud-4) sdlo = ud-4;
            if (sdhi > ud)   sdhi = ud;
            if (sylo < uy-2) sylo = uy-2;
            if (syhi > uy)   syhi = uy;
            if (sxlo < ux-2) sxlo = ux-2;
            if (sxhi > ux)   sxhi = ux;
            float acc = 0.f;
            for (int sd = sdlo; sd <= sdhi; ++sd)
                for (int sy = sylo; sy <= syhi; ++sy)
                    for (int sx = sxlo; sx <= sxhi; ++sx)
                        acc += TL[(sd*9+sy*3+sx)*45 + (ud-sd)*9 + (uy-sy)*3 + (ux-sx)];
            ws[WS_WEFF + idx] = acc;
        }
    }

    // ---- M[cls][i][j] = sum_e r2c[cls][e]*W2[e][i][j], partitioned ----
    {
        const int c0 = bid*241, c1 = (c0+241 < 3844) ? c0+241 : 3844;
        for (int idx = c0 + tid; idx < c1; idx += 256) {
            int cls = idx / 961, ij = idx % 961;
            float acc = 0.f;
            #pragma unroll
            for (int e = 0; e < 4; ++e) acc += r2cL[cls*4+e]*W2[e*961+ij];
            ws[WS_M + idx] = acc;
        }
    }
}

// ---------------------------------------------------------------------------
// Conv partial: each thread handles a subset of the 25 (uy,ux) taps over all
// 31 depths. INTERIOR => statically-uniform weight indices => s_load (scalar
// pipe), zero LDS/vector traffic for weights.
// ---------------------------------------------------------------------------
template<bool INTER>
__device__ __forceinline__ void conv_part(const float fs[31][12][24],
                                          const float* __restrict__ wg,
                                          int bc, int ly, int lx, int sub,
                                          float o2[31])
{
    const int t0 = sub ? 13 : 0, t1 = sub ? 25 : 13;
    #pragma unroll 1
    for (int t = t0; t < t1; ++t) {
        const int uy = t / 5, ux = t - uy*5;
        float col[39];
        #pragma unroll
        for (int i = 0; i < 4; ++i) { col[i] = 0.f; col[35+i] = 0.f; }
        const float* f0 = &fs[0][ly+uy][lx+ux];
        #pragma unroll
        for (int i = 0; i < 31; ++i) col[4+i] = f0[i*288];

        float wA[5][9];
        #pragma unroll
        for (int a = 0; a < 5; ++a) {
            const int cfg = INTER ? (a*9 + 4) : (a*9 + bc);
            #pragma unroll
            for (int ud = 0; ud < 9; ++ud) wA[a][ud] = wg[cfg*225 + ud*25 + t];
        }
        #pragma unroll
        for (int ud = 0; ud < 9; ++ud) {
            o2[0]  += wA[0][ud] * col[ud];
            o2[1]  += wA[1][ud] * col[1+ud];
            o2[29] += wA[3][ud] * col[29+ud];
            o2[30] += wA[4][ud] * col[30+ud];
        }
        #pragma unroll
        for (int d = 2; d < 29; ++d) {
            #pragma unroll
            for (int ud = 0; ud < 9; ++ud)
                o2[d] += wA[2][ud] * col[d+ud];
        }
    }
}

// ---------------------------------------------------------------------------
// Kernel B: 512 blocks (8x16 tile), 256 threads, 2 threads/pixel. Bilinear
// fill -> split composed conv -> LDS combine -> split 31x31 mix.
// ---------------------------------------------------------------------------
__global__ __launch_bounds__(256, 2)
void fused_kernel(const float* __restrict__ x, const float* __restrict__ ws,
                  float* __restrict__ out)
{
    __shared__ float fs[31][12][24];   // 35.7 KB (cols 0..19 used; 24 = 2-way bank stride)
    __shared__ float Ms[3844];         // 15.4 KB
    __shared__ float o2p[128][31];     // 15.9 KB
    const int tid = threadIdx.x;
    const int x0 = blockIdx.x * 16;
    const int y0 = blockIdx.y * 8;

    float off0[4], off1[4];
    #pragma unroll
    for (int c = 0; c < 4; ++c) { off0[c] = ws[WS_OFF+c]; off1[c] = ws[WS_OFF+4+c]; }

    for (int idx = tid; idx < 3844; idx += 256) Ms[idx] = ws[WS_M + idx];

    // ---- bilinear fill of the fea tile ----
    for (int idx = tid; idx < 7440; idx += 256) {
        int c  = idx / 240;
        int r  = idx % 240;
        int yy = r / 20, xx = r % 20;
        int gy = y0 + yy - 2, gx = x0 + xx - 2;
        float v = 0.f;
        if (gy >= 0 && gy < 256 && gx >= 0 && gx < 256) {
            int cls = ((gy & 1) << 1) | (gx & 1);
            float ix = (gx + 0.5f)*0.5f - 0.5f + off0[cls];
            float iy = (gy + 0.5f)*0.5f - 0.5f + off1[cls];
            float xf = floorf(ix), yf = floorf(iy);
            float wx = ix - xf, wy = iy - yf;
            int xi = (int)xf, yi = (int)yf;
            const float* xc = x + c*16384;
            float acc = 0.f;
            if (yi   >= 0 && yi   < 128 && xi   >= 0 && xi   < 128) acc += xc[yi*128+xi]       * (1.f-wy)*(1.f-wx);
            if (yi   >= 0 && yi   < 128 && xi+1 >= 0 && xi+1 < 128) acc += xc[yi*128+xi+1]     * (1.f-wy)*wx;
            if (yi+1 >= 0 && yi+1 < 128 && xi   >= 0 && xi   < 128) acc += xc[(yi+1)*128+xi]   * wy*(1.f-wx);
            if (yi+1 >= 0 && yi+1 < 128 && xi+1 >= 0 && xi+1 < 128) acc += xc[(yi+1)*128+xi+1] * wy*wx;
            v = acc;
        }
        fs[c][yy][xx] = v;
    }
    __syncthreads();

    const int px = tid & 127, sub = tid >> 7;
    const int lx = px & 15,  ly = px >> 4;
    const int gx = x0 + lx,  gy = y0 + ly;
    const int bcls = (gy == 0) ? 0 : ((gy == 255) ? 2 : 1);
    const int ccls = (gx == 0) ? 0 : ((gx == 255) ? 2 : 1);
    const int bc = bcls*3 + ccls;
    const float* wg = ws + WS_WEFF;

    float o2[31];
    if (sub == 0) {
        #pragma unroll
        for (int d = 0; d < 31; ++d) o2[d] = fs[d][ly+2][lx+2];   // conv2 residual (+fea)
    } else {
        #pragma unroll
        for (int d = 0; d < 31; ++d) o2[d] = 0.f;
    }

    const bool inter = (x0 != 0) & (x0 != 240) & (y0 != 0) & (y0 != 248);
    if (inter) conv_part<true >(fs, wg, bc, ly, lx, sub, o2);
    else       conv_part<false>(fs, wg, bc, ly, lx, sub, o2);

    if (sub) {
        #pragma unroll
        for (int d = 0; d < 31; ++d) o2p[px][d] = o2[d];
    }
    __syncthreads();
    if (!sub) {
        #pragma unroll
        for (int d = 0; d < 31; ++d) o2[d] += o2p[px][d];
        #pragma unroll
        for (int d = 0; d < 31; ++d) o2p[px][d] = o2[d];
    }
    __syncthreads();

    // ---- mix: out[i] = sum_j M[cls][i][j]*o2[j] + fea0[i], rows split ----
    const int cls = ((gy & 1) << 1) | (gx & 1);
    const int i0 = sub ? 16 : 0, i1 = sub ? 31 : 16;
    #pragma unroll 1
    for (int i = i0; i < i1; ++i) {
        float acc = fs[i][ly+2][lx+2];
        #pragma unroll
        for (int j = 0; j < 31; ++j) acc += Ms[cls*961 + i*31 + j] * o2p[px][j];
        out[i*65536 + gy*256 + gx] = acc;
    }
}

extern "C" void kernel_launch(void* const* d_in, const int* in_sizes, int n_in,
                              void* d_out, int out_size, void* d_ws, size_t ws_size,
                              hipStream_t stream)
{
    const float* x   = (const float*)d_in[0];
    // d_in[1] = scale (int, always 2; shapes are compile-time)
    const float* WE  = (const float*)d_in[2];
    const float* WC  = (const float*)d_in[3];
    const float* W2  = (const float*)d_in[4];
    const float* bw1 = (const float*)d_in[5];
    const float* bb1 = (const float*)d_in[6];
    const float* bw2 = (const float*)d_in[7];
    const float* bb2 = (const float*)d_in[8];
    const float* r2w = (const float*)d_in[9];
    const float* r2b = (const float*)d_in[10];
    const float* ow  = (const float*)d_in[11];
    const float* ob  = (const float*)d_in[12];
    const float* l1w = (const float*)d_in[13];
    const float* l1b = (const float*)d_in[14];
    const float* l2w = (const float*)d_in[15];
    const float* l2b = (const float*)d_in[16];
    float* ws  = (float*)d_ws;
    float* out = (float*)d_out;

    hipLaunchKernelGGL(prep_kernel, dim3(16), dim3(256), 0, stream,
                       WE, WC, W2, bw1, bb1, bw2, bb2, r2w, r2b,
                       ow, ob, l1w, l1b, l2w, l2b, ws);
    hipLaunchKernelGGL(fused_kernel, dim3(16, 32), dim3(256), 0, stream,
                       x, ws, out);
}

// Round 6
// 170.589 us; speedup vs baseline: 1.6010x; 1.0158x over previous
//
#include <hip/hip_runtime.h>
#include <math.h>

// ---------------------------------------------------------------------------
// Single mega-kernel: each of 512 blocks (8x16 output tile) redundantly does
// the tiny prep (routing softmax -> we/wc -> T -> its <=4 border-class
// composed-kernel slices -> parity MLP -> mix matrices), then bilinear fill,
// composed 9x5x5 conv (2 threads/pixel tap-split), and the 31x31 mix.
// LDS region A (7812 f) is time-multiplexed: [weL|wcL|TL] -> fs -> o2p.
// ---------------------------------------------------------------------------

#define LDS_TOTAL 16448
#define O_A      0        // 7812 floats: prep arrays / fs tile / o2p overlay
#define O_WEFF   7812     // 4500: weffC[4][5][225]
#define O_MS     12312    // 3844: Ms[4][961]
#define O_E1     16156    // 256:  e1L[4][64]
#define O_R2C    16412    // 16:   r2cL[4][4]
#define O_SMALL  16428    // 20:   rsum[4] | logits[8] | offs[8]

__device__ __forceinline__ void fill_weff_slot(float* __restrict__ dst,
                                               const float* __restrict__ TL,
                                               int bS, int cS, int tid)
{
    for (int idx = tid; idx < 1125; idx += 256) {
        int a = idx / 225, u = idx % 225;
        int ud = u/25, uy = (u%25)/5, ux = u%5;
        int sdlo = (a==0)?2:((a==1)?1:0);
        int sdhi = (a==4)?2:((a==3)?3:4);
        int sylo = (bS==0)?1:0, syhi = (bS==2)?1:2;
        int sxlo = (cS==0)?1:0, sxhi = (cS==2)?1:2;
        if (sdlo < ud-4) sdlo = ud-4;
        if (sdhi > ud)   sdhi = ud;
        if (sylo < uy-2) sylo = uy-2;
        if (syhi > uy)   syhi = uy;
        if (sxlo < ux-2) sxlo = ux-2;
        if (sxhi > ux)   sxhi = ux;
        float acc = 0.f;
        for (int sd = sdlo; sd <= sdhi; ++sd)
            for (int sy = sylo; sy <= syhi; ++sy)
                for (int sx = sxlo; sx <= sxhi; ++sx)
                    acc += TL[(sd*9+sy*3+sx)*45 + (ud-sd)*9 + (uy-sy)*3 + (ux-sx)];
        dst[idx] = acc;
    }
}

__device__ __forceinline__ void conv_part(const float* __restrict__ fsA,
                                          const float* __restrict__ wgt,
                                          int ly, int lx, int sub, float o2[31])
{
    const int t0 = sub ? 13 : 0, t1 = sub ? 25 : 13;
    #pragma unroll 1
    for (int t = t0; t < t1; ++t) {
        const int uy = t / 5, ux = t - uy*5;
        float col[39];
        #pragma unroll
        for (int i = 0; i < 4; ++i) { col[i] = 0.f; col[35+i] = 0.f; }
        const float* f0 = fsA + (ly+uy)*21 + (lx+ux);
        #pragma unroll
        for (int i = 0; i < 31; ++i) col[4+i] = f0[i*252];

        float wA[5][9];
        #pragma unroll
        for (int a = 0; a < 5; ++a) {
            #pragma unroll
            for (int ud = 0; ud < 9; ++ud) wA[a][ud] = wgt[a*225 + ud*25 + t];
        }
        #pragma unroll
        for (int ud = 0; ud < 9; ++ud) {
            o2[0]  += wA[0][ud] * col[ud];
            o2[1]  += wA[1][ud] * col[1+ud];
            o2[29] += wA[3][ud] * col[29+ud];
            o2[30] += wA[4][ud] * col[30+ud];
        }
        #pragma unroll
        for (int d = 2; d < 29; ++d) {
            #pragma unroll
            for (int ud = 0; ud < 9; ++ud)
                o2[d] += wA[2][ud] * col[d+ud];
        }
    }
}

__global__ __launch_bounds__(256, 2)
void mega_kernel(const float* __restrict__ x,
    const float* __restrict__ WE,  const float* __restrict__ WC,
    const float* __restrict__ W2,
    const float* __restrict__ bw1, const float* __restrict__ bb1,
    const float* __restrict__ bw2, const float* __restrict__ bb2,
    const float* __restrict__ r2w, const float* __restrict__ r2b,
    const float* __restrict__ ow,  const float* __restrict__ ob,
    const float* __restrict__ l1w, const float* __restrict__ l1b,
    const float* __restrict__ l2w, const float* __restrict__ l2b,
    float* __restrict__ out)
{
    __shared__ float lds[LDS_TOTAL];
    float* weL   = lds + O_A;          // 1440
    float* wcL   = lds + O_A + 1440;   // 1440
    float* TL    = lds + O_A + 2880;   // 2025
    float* fsA   = lds + O_A;          // fs[d][yy][xx] = fsA[d*252+yy*21+xx]
    float* o2p   = lds + O_A;          // o2p[px*31+d] (overlays fs after conv)
    float* weffC = lds + O_WEFF;
    float* Ms    = lds + O_MS;
    float* e1L   = lds + O_E1;
    float* r2cL  = lds + O_R2C;
    float* rsumS = lds + O_SMALL;
    float* logitsL = lds + O_SMALL + 4;
    float* offS  = lds + O_SMALL + 12;

    const int tid  = threadIdx.x;
    const int lane = tid & 63, wid = tid >> 6;
    const int x0 = blockIdx.x * 16;
    const int y0 = blockIdx.y * 8;

    // ---- stage0: routing logits (waves 0,1) + body MLP layer1 (wid = parity cls)
    if (wid < 2) {
        float chv = wid ? 0.25f : -0.25f;
        int o = lane;
        float h = fmaxf(0.5f*l1w[2*o] + chv*l1w[2*o+1] + l1b[o], 0.f);
        float a0 = h*l2w[o], a1 = h*l2w[64+o], a2 = h*l2w[128+o], a3 = h*l2w[192+o];
        for (int off = 32; off; off >>= 1) {
            a0 += __shfl_down(a0, off); a1 += __shfl_down(a1, off);
            a2 += __shfl_down(a2, off); a3 += __shfl_down(a3, off);
        }
        if (lane == 0) {
            logitsL[wid*4+0] = a0 + l2b[0]; logitsL[wid*4+1] = a1 + l2b[1];
            logitsL[wid*4+2] = a2 + l2b[2]; logitsL[wid*4+3] = a3 + l2b[3];
        }
    }
    {
        float chv = (wid & 2) ? 0.25f : -0.25f;   // y parity
        float cwv = (wid & 1) ? 0.25f : -0.25f;   // x parity
        int o = lane;
        e1L[wid*64+o] = fmaxf(0.5f*bw1[3*o] + chv*bw1[3*o+1] + cwv*bw1[3*o+2] + bb1[o], 0.f);
    }
    __syncthreads();

    // ---- stage1: softmax rsum (tid0) + MLP layer2/offsets/r2 (wave reductions)
    if (tid == 0) {
        float rs[4] = {0.f,0.f,0.f,0.f};
        for (int r = 0; r < 2; ++r) {
            float l0=logitsL[r*4+0], l1v=logitsL[r*4+1], l2v=logitsL[r*4+2], l3=logitsL[r*4+3];
            float mx = fmaxf(fmaxf(l0,l1v), fmaxf(l2v,l3));
            float e0=expf(l0-mx), e1=expf(l1v-mx), e2=expf(l2v-mx), e3=expf(l3-mx);
            float s = e0+e1+e2+e3;
            rs[0]+=e0/s; rs[1]+=e1/s; rs[2]+=e2/s; rs[3]+=e3/s;
        }
        rsumS[0]=rs[0]; rsumS[1]=rs[1]; rsumS[2]=rs[2]; rsumS[3]=rs[3];
    }
    {
        int o = lane;
        float acc = bb2[o];
        #pragma unroll 8
        for (int i = 0; i < 64; ++i) acc += e1L[wid*64+i]*bw2[o*64+i];
        float e2v = fmaxf(acc, 0.f);
        float v0 = e2v*ow[o],       v1 = e2v*ow[64+o];
        float r0 = e2v*r2w[o],      r1 = e2v*r2w[64+o];
        float r2v= e2v*r2w[128+o],  r3 = e2v*r2w[192+o];
        for (int off = 32; off; off >>= 1) {
            v0 += __shfl_down(v0, off);  v1 += __shfl_down(v1, off);
            r0 += __shfl_down(r0, off);  r1 += __shfl_down(r1, off);
            r2v+= __shfl_down(r2v, off); r3 += __shfl_down(r3, off);
        }
        if (lane == 0) {
            offS[wid]     = v0 + ob[0];   // x offset, cls=wid
            offS[4 + wid] = v1 + ob[1];   // y offset
            r2cL[wid*4+0] = 1.f/(1.f+expf(-(r0 + r2b[0])));
            r2cL[wid*4+1] = 1.f/(1.f+expf(-(r1 + r2b[1])));
            r2cL[wid*4+2] = 1.f/(1.f+expf(-(r2v+ r2b[2])));
            r2cL[wid*4+3] = 1.f/(1.f+expf(-(r3 + r2b[3])));
        }
    }
    __syncthreads();

    // ---- stage2: we/wc (routing-combined) + Ms (mix matrices)
    {
        float rs0=rsumS[0], rs1=rsumS[1], rs2=rsumS[2], rs3=rsumS[3];
        for (int idx = tid; idx < 1440; idx += 256) {
            weL[idx] = rs0*WE[idx] + rs1*WE[1440+idx] + rs2*WE[2880+idx] + rs3*WE[4320+idx];
            wcL[idx] = rs0*WC[idx] + rs1*WC[1440+idx] + rs2*WC[2880+idx] + rs3*WC[4320+idx];
        }
    }
    for (int idx = tid; idx < 3844; idx += 256) {
        int cls = idx / 961, ij = idx % 961;
        float acc = 0.f;
        #pragma unroll
        for (int e = 0; e < 4; ++e) acc += r2cL[cls*4+e]*W2[e*961+ij];
        Ms[idx] = acc;
    }
    __syncthreads();

    // ---- stage3: T[s][t] = sum_k wc[k][s]*we[k][t]
    for (int idx = tid; idx < 2025; idx += 256) {
        int s = idx / 45, t = idx % 45;
        float acc = 0.f;
        #pragma unroll 8
        for (int k = 0; k < 32; ++k) acc += wcL[k*45+s] * weL[k*45+t];
        TL[idx] = acc;
    }
    __syncthreads();

    // ---- stage4: this block's composed-kernel slices (<=4 border classes)
    {
        const int  ybE  = (y0==0) ? 0 : 2;
        const int  xcE  = (x0==0) ? 0 : 2;
        const bool needY = (y0==0) || (y0==248);
        const bool needX = (x0==0) || (x0==240);
        fill_weff_slot(weffC, TL, 1, 1, tid);
        if (needX)          fill_weff_slot(weffC+1125, TL, 1,   xcE, tid);
        if (needY)          fill_weff_slot(weffC+2250, TL, ybE, 1,   tid);
        if (needX && needY) fill_weff_slot(weffC+3375, TL, ybE, xcE, tid);
    }
    __syncthreads();

    // ---- stage5: bilinear fill of fs (overwrites weL/wcL/TL region)
    {
        float off0[4], off1[4];
        #pragma unroll
        for (int c = 0; c < 4; ++c) { off0[c] = offS[c]; off1[c] = offS[4+c]; }
        for (int idx = tid; idx < 7440; idx += 256) {
            int c  = idx / 240;
            int r  = idx % 240;
            int yy = r / 20, xx = r % 20;
            int gy = y0 + yy - 2, gx = x0 + xx - 2;
            float v = 0.f;
            if (gy >= 0 && gy < 256 && gx >= 0 && gx < 256) {
                int cls = ((gy & 1) << 1) | (gx & 1);
                float ix = (gx + 0.5f)*0.5f - 0.5f + off0[cls];
                float iy = (gy + 0.5f)*0.5f - 0.5f + off1[cls];
                float xf = floorf(ix), yf = floorf(iy);
                float wx = ix - xf, wy = iy - yf;
                int xi = (int)xf, yi = (int)yf;
                const float* xc = x + c*16384;
                float acc = 0.f;
                if (yi   >= 0 && yi   < 128 && xi   >= 0 && xi   < 128) acc += xc[yi*128+xi]       * (1.f-wy)*(1.f-wx);
                if (yi   >= 0 && yi   < 128 && xi+1 >= 0 && xi+1 < 128) acc += xc[yi*128+xi+1]     * (1.f-wy)*wx;
                if (yi+1 >= 0 && yi+1 < 128 && xi   >= 0 && xi   < 128) acc += xc[(yi+1)*128+xi]   * wy*(1.f-wx);
                if (yi+1 >= 0 && yi+1 < 128 && xi+1 >= 0 && xi+1 < 128) acc += xc[(yi+1)*128+xi+1] * wy*wx;
                v = acc;
            }
            fsA[c*252 + yy*21 + xx] = v;
        }
    }
    __syncthreads();

    // ---- stage6: composed conv (2 threads/pixel, tap split 13/12)
    const int px = tid & 127, sub = tid >> 7;
    const int lx = px & 15,  ly = px >> 4;
    const int gx = x0 + lx,  gy = y0 + ly;
    const int ySlot = ((gy==0) | (gy==255)) ? 1 : 0;
    const int xSlot = ((gx==0) | (gx==255)) ? 1 : 0;
    const int slot  = ySlot*2 + xSlot;

    float o2[31];
    if (sub == 0) {
        #pragma unroll
        for (int d = 0; d < 31; ++d) o2[d] = fsA[d*252 + (ly+2)*21 + (lx+2)];  // conv2 residual (+fea)
    } else {
        #pragma unroll
        for (int d = 0; d < 31; ++d) o2[d] = 0.f;
    }
    conv_part(fsA, weffC + slot*1125, ly, lx, sub, o2);

    // stash fea0 residual for my mix rows before o2p overlays fs
    const int i0 = sub ? 16 : 0, i1 = sub ? 31 : 16;
    float fsc[16];
    #pragma unroll
    for (int k = 0; k < 16; ++k) {
        int i = i0 + k;
        fsc[k] = (i < i1) ? fsA[i*252 + (ly+2)*21 + (lx+2)] : 0.f;
    }
    __syncthreads();   // all fs reads complete; region A becomes o2p

    if (sub) {
        #pragma unroll
        for (int d = 0; d < 31; ++d) o2p[px*31+d] = o2[d];
    }
    __syncthreads();
    if (!sub) {
        #pragma unroll
        for (int d = 0; d < 31; ++d) o2[d] += o2p[px*31+d];
        #pragma unroll
        for (int d = 0; d < 31; ++d) o2p[px*31+d] = o2[d];
    }
    __syncthreads();

    // ---- stage7: mix, rows split 16/15
    const int cls = ((gy & 1) << 1) | (gx & 1);
    #pragma unroll 1
    for (int k = 0; k < 16; ++k) {
        int i = i0 + k;
        if (i < i1) {
            float acc = fsc[k];
            #pragma unroll
            for (int j = 0; j < 31; ++j) acc += Ms[cls*961 + i*31 + j] * o2p[px*31+j];
            out[i*65536 + gy*256 + gx] = acc;
        }
    }
}

extern "C" void kernel_launch(void* const* d_in, const int* in_sizes, int n_in,
                              void* d_out, int out_size, void* d_ws, size_t ws_size,
                              hipStream_t stream)
{
    const float* x   = (const float*)d_in[0];
    // d_in[1] = scale (int, always 2; shapes are compile-time)
    const float* WE  = (const float*)d_in[2];
    const float* WC  = (const float*)d_in[3];
    const float* W2  = (const float*)d_in[4];
    const float* bw1 = (const float*)d_in[5];
    const float* bb1 = (const float*)d_in[6];
    const float* bw2 = (const float*)d_in[7];
    const float* bb2 = (const float*)d_in[8];
    const float* r2w = (const float*)d_in[9];
    const float* r2b = (const float*)d_in[10];
    const float* ow  = (const float*)d_in[11];
    const float* ob  = (const float*)d_in[12];
    const float* l1w = (const float*)d_in[13];
    const float* l1b = (const float*)d_in[14];
    const float* l2w = (const float*)d_in[15];
    const float* l2b = (const float*)d_in[16];
    float* out = (float*)d_out;

    hipLaunchKernelGGL(mega_kernel, dim3(16, 32), dim3(256), 0, stream,
                       x, WE, WC, W2, bw1, bb1, bw2, bb2, r2w, r2b,
                       ow, ob, l1w, l1b, l2w, l2b, out);
}